// Round 9
// baseline (728.326 us; speedup 1.0000x reference)
//
#include <hip/hip_runtime.h>

#define FIN 64
#define HID 256
#define DEMB 128
#define NLAYERS 3

typedef __attribute__((ext_vector_type(8))) short bf16x8;
typedef __attribute__((ext_vector_type(4))) float f32x4;

__device__ inline short f2bf(float x) {               // RNE fp32 -> bf16 bits
    unsigned u = __float_as_uint(x);
    u += 0x7fff + ((u >> 16) & 1);
    return (short)(u >> 16);
}
__device__ inline float bf2f(short h) {
    return __uint_as_float(((unsigned)(unsigned short)h) << 16);
}

// Activation layout "q-pack": per row r, 512 shorts (1KB contiguous):
//   h of col c at r*512 + (c>>2)*8 + (c&3);  l at +4.
// One uint4 (16B) = h+l of 4 consecutive cols -> single gather load per lane.
// Stored values are PRE-SCALED by dinv[row] except after the last layer.

// sum 4 cols (h+l recon) of packed uint4 into acc
#define QACC(V) do { \
    acc.x += __uint_as_float((V).x << 16) + __uint_as_float((V).z << 16); \
    acc.y += __uint_as_float((V).x & 0xffff0000u) + __uint_as_float((V).z & 0xffff0000u); \
    acc.z += __uint_as_float((V).y << 16) + __uint_as_float((V).w << 16); \
    acc.w += __uint_as_float((V).y & 0xffff0000u) + __uint_as_float((V).w & 0xffff0000u); } while (0)

// ---------------- small graph-prep kernels ----------------

__global__ __launch_bounds__(256) void zero_kernel(int* counts, int n, float* pool_sum, int* pool_max) {
    int i = blockIdx.x * 256 + threadIdx.x;
    if (i < n) counts[i] = 0;
    if (i < HID) { pool_sum[i] = 0.0f; pool_max[i] = 0; }
}

__global__ __launch_bounds__(256) void hist_kernel(const int* __restrict__ ei, int E, int* __restrict__ counts) {
    int e = blockIdx.x * 256 + threadIdx.x;
    if (e < E) atomicAdd(&counts[ei[E + e]], 1);
}

__global__ __launch_bounds__(256) void scan_partial(const int* __restrict__ counts, int n,
                                                    int* __restrict__ chunkSums, float* __restrict__ dinv) {
    __shared__ int s[256];
    int t = threadIdx.x, base = blockIdx.x * 1024;
    int sum = 0;
#pragma unroll
    for (int j = 0; j < 4; j++) {
        int i = base + t * 4 + j;
        if (i < n) {
            int c = counts[i];
            sum += c;
            dinv[i] = rsqrtf((float)(c + 1));
        }
    }
    s[t] = sum; __syncthreads();
    for (int off = 128; off > 0; off >>= 1) { if (t < off) s[t] += s[t + off]; __syncthreads(); }
    if (t == 0) chunkSums[blockIdx.x] = s[0];
}

__global__ void scan_sums(int* cs, int nch) {
    int l = threadIdx.x;
    int orig = (l < nch) ? cs[l] : 0;
    int v = orig;
    for (int off = 1; off < 64; off <<= 1) {
        int x = __shfl_up(v, off, 64);
        if (l >= off) v += x;
    }
    if (l < nch) cs[l] = v - orig;
}

__global__ __launch_bounds__(256) void scan_final(const int* __restrict__ counts, int n,
                                                  const int* __restrict__ chunkOff, int* __restrict__ row_ptr,
                                                  int* __restrict__ cursor) {
    __shared__ int s[256];
    int t = threadIdx.x, base = blockIdx.x * 1024;
    int v[4]; int sum = 0;
#pragma unroll
    for (int j = 0; j < 4; j++) { int i = base + t * 4 + j; v[j] = (i < n) ? counts[i] : 0; sum += v[j]; }
    s[t] = sum; __syncthreads();
    for (int off = 1; off < 256; off <<= 1) {
        int x = (t >= off) ? s[t - off] : 0;
        __syncthreads();
        s[t] += x;
        __syncthreads();
    }
    int run = chunkOff[blockIdx.x] + (s[t] - sum);
#pragma unroll
    for (int j = 0; j < 4; j++) {
        int i = base + t * 4 + j;
        if (i < n) {
            row_ptr[i] = run; cursor[i] = run; run += v[j];
            if (i == n - 1) row_ptr[n] = run;
        }
    }
}

__global__ __launch_bounds__(256) void fill_kernel(const int* __restrict__ ei, int E,
                                                   int* __restrict__ cursor, int* __restrict__ adj) {
    int e = blockIdx.x * 256 + threadIdx.x;
    if (e < E) {
        int s = ei[e], d = ei[E + e];
        int p = atomicAdd(&cursor[d], 1);
        adj[p] = s;
    }
}

// ---------------- weight packing (slab-major, B-side; unchanged) --------------

__global__ __launch_bounds__(256) void pack_all(const float* __restrict__ W1, const float* __restrict__ W2,
                                                const float* __restrict__ Wc,
                                                short* __restrict__ PH, short* __restrict__ PL) {
    int b = blockIdx.x, n = threadIdx.x;
    const float* src; int k; size_t dst;
    if (b < 64) { src = W1; k = b; dst = 0; }
    else {
        int m = (b - 64) >> 8; k = (b - 64) & 255;
        src = (m == 0) ? W2 : (Wc + (size_t)(m - 1) * 65536);
        dst = 16384 + (size_t)m * 65536;
    }
    float w = src[(size_t)k * 256 + n];
    short h = f2bf(w);
    short l = f2bf(w - bf2f(h));
    int o = ((k >> 3) * 256 + n) * 8 + (k & 7);
    PH[dst + o] = h; PL[dst + o] = l;
}

// ---------------- split-bf16 MFMA GEMM, fp32 A (encoder) ------------
// OUTP: write q-pack activation; SCALEP: pre-scale by dinv[row].

template<int K, bool RELU, bool BIAS, bool OUTP, bool SCALEP>
__global__ __launch_bounds__(256) void gemm_conv(const float* __restrict__ A,
                                                 const short* __restrict__ PBh, const short* __restrict__ PBl,
                                                 const float* __restrict__ bias,
                                                 float* __restrict__ Cf, short* __restrict__ Cp,
                                                 const float* __restrict__ dinv, int M) {
    __shared__ short AhL[4][64][8];
    __shared__ short AlL[4][64][8];
    int t = threadIdx.x;
    int lane = t & 63, wave = t >> 6;
    int brow = blockIdx.x * 64;
    int bcol = wave * 64;
    int lr = lane & 15, lg = lane >> 4;
    f32x4 acc[4][4] = {};

    constexpr int NS = K / 32;
    float4 a_pre[2];
#pragma unroll
    for (int l = 0; l < 2; l++) {
        int lin = t + l * 256;
        int r = lin >> 3, kq = (lin & 7) * 4;
        int row = brow + r;
        a_pre[l] = (row < M) ? *(const float4*)(A + (size_t)row * K + kq)
                             : make_float4(0.f, 0.f, 0.f, 0.f);
    }

    for (int s = 0; s < NS; ++s) {
#pragma unroll
        for (int l = 0; l < 2; l++) {
            int lin = t + l * 256;
            int r = lin >> 3, kq = (lin & 7) * 4;
            int g = kq >> 3, i0 = kq & 7;
            float4 v = a_pre[l];
            short h0 = f2bf(v.x), h1 = f2bf(v.y), h2 = f2bf(v.z), h3 = f2bf(v.w);
            short e0 = f2bf(v.x - bf2f(h0)), e1 = f2bf(v.y - bf2f(h1));
            short e2 = f2bf(v.z - bf2f(h2)), e3 = f2bf(v.w - bf2f(h3));
            uint2 hw, lw;
            hw.x = (unsigned short)h0 | ((unsigned)(unsigned short)h1 << 16);
            hw.y = (unsigned short)h2 | ((unsigned)(unsigned short)h3 << 16);
            lw.x = (unsigned short)e0 | ((unsigned)(unsigned short)e1 << 16);
            lw.y = (unsigned short)e2 | ((unsigned)(unsigned short)e3 << 16);
            *(uint2*)&AhL[g][r][i0] = hw;
            *(uint2*)&AlL[g][r][i0] = lw;
        }
        const short* pbh = PBh + ((size_t)(s * 4 + lg) * 256 + bcol + lr) * 8;
        const short* pbl = PBl + ((size_t)(s * 4 + lg) * 256 + bcol + lr) * 8;
        bf16x8 bh[4], bl[4];
#pragma unroll
        for (int ni = 0; ni < 4; ni++) {
            bh[ni] = *(const bf16x8*)(pbh + ni * 128);
            bl[ni] = *(const bf16x8*)(pbl + ni * 128);
        }
        if (s + 1 < NS) {
#pragma unroll
            for (int l = 0; l < 2; l++) {
                int lin = t + l * 256;
                int r = lin >> 3, kq = (lin & 7) * 4;
                int row = brow + r;
                a_pre[l] = (row < M) ? *(const float4*)(A + (size_t)row * K + (s + 1) * 32 + kq)
                                     : make_float4(0.f, 0.f, 0.f, 0.f);
            }
        }
        __syncthreads();
        bf16x8 ah[4], al[4];
#pragma unroll
        for (int mi = 0; mi < 4; mi++) {
            ah[mi] = *(bf16x8*)&AhL[lg][mi * 16 + lr][0];
            al[mi] = *(bf16x8*)&AlL[lg][mi * 16 + lr][0];
        }
#pragma unroll
        for (int mi = 0; mi < 4; mi++)
#pragma unroll
            for (int ni = 0; ni < 4; ni++) {
                acc[mi][ni] = __builtin_amdgcn_mfma_f32_16x16x32_bf16(ah[mi], bh[ni], acc[mi][ni], 0, 0, 0);
                acc[mi][ni] = __builtin_amdgcn_mfma_f32_16x16x32_bf16(ah[mi], bl[ni], acc[mi][ni], 0, 0, 0);
                acc[mi][ni] = __builtin_amdgcn_mfma_f32_16x16x32_bf16(al[mi], bh[ni], acc[mi][ni], 0, 0, 0);
            }
        if (s + 1 < NS) __syncthreads();
    }

#pragma unroll
    for (int ni = 0; ni < 4; ni++) {
        int col = bcol + ni * 16 + lr;
        float bv = BIAS ? bias[col] : 0.f;
#pragma unroll
        for (int mi = 0; mi < 4; mi++)
#pragma unroll
            for (int j = 0; j < 4; j++) {
                int row = brow + mi * 16 + lg * 4 + j;
                if (row < M) {
                    float o = acc[mi][ni][j] + bv;
                    if (RELU) o = fmaxf(o, 0.f);
                    if (OUTP) {
                        if (SCALEP) o *= dinv[row];
                        short hh = f2bf(o);
                        short hl = f2bf(o - bf2f(hh));
                        size_t off = (size_t)row * 512 + (col >> 2) * 8 + (col & 3);
                        Cp[off] = hh; Cp[off + 4] = hl;
                    } else {
                        Cf[(size_t)row * 256 + col] = o;
                    }
                }
            }
    }
}

// ---------------- fused GCN layer: out = relu((S@h)@Wc + b) -------------------
// Input q-pack PRE-SCALED by dinv => gather is a pure uint4 row sum.
// BM=16 rows/block, 4 waves. LDS aliased: A-frags (8704 sh) / out tile (8192 sh).
// SCALE_OUT: multiply output by dinv[row] (all but last layer).

template<bool SCALE_OUT>
__global__ __launch_bounds__(256) void layer_fused(const short* __restrict__ Ain,
                                                   const int* __restrict__ row_ptr, const int* __restrict__ adj,
                                                   const float* __restrict__ dinv,
                                                   const short* __restrict__ PBh, const short* __restrict__ PBl,
                                                   const float* __restrict__ bias,
                                                   short* __restrict__ Aout, int n) {
    __shared__ short LB[8704];
    int t = threadIdx.x, lane = t & 63, wv = t >> 6;
    int lr = lane & 15, lg = lane >> 4;
    int brow = blockIdx.x * 16;
    int slab = lane >> 1, i0 = (lane & 1) * 4;

    // ---- phase 1: gather + sum (each wave: 4 dst rows; 8-deep, 16B loads) ----
    for (int it = 0; it < 4; ++it) {
        int r = wv * 4 + it, v = brow + r;
        if (v >= n) break;                       // wave-uniform
        float dv = dinv[v];
        uint4 V0 = *(const uint4*)(Ain + (size_t)v * 512 + lane * 8);
        float4 acc;
        acc.x = __uint_as_float(V0.x << 16) + __uint_as_float(V0.z << 16);
        acc.y = __uint_as_float(V0.x & 0xffff0000u) + __uint_as_float(V0.z & 0xffff0000u);
        acc.z = __uint_as_float(V0.y << 16) + __uint_as_float(V0.w << 16);
        acc.w = __uint_as_float(V0.y & 0xffff0000u) + __uint_as_float(V0.w & 0xffff0000u);
        int e = row_ptr[v], end = row_ptr[v + 1];
        for (; e + 8 <= end; e += 8) {
            int s8[8]; uint4 V[8];
#pragma unroll
            for (int j = 0; j < 8; j++) s8[j] = adj[e + j];
#pragma unroll
            for (int j = 0; j < 8; j++) V[j] = *(const uint4*)(Ain + (size_t)s8[j] * 512 + lane * 8);
#pragma unroll
            for (int j = 0; j < 8; j++) QACC(V[j]);
        }
        for (; e < end; e++) {
            int s0 = adj[e];
            uint4 V = *(const uint4*)(Ain + (size_t)s0 * 512 + lane * 8);
            QACC(V);
        }
        float a0 = dv * acc.x, a1 = dv * acc.y, a2 = dv * acc.z, a3 = dv * acc.w;
        short h0 = f2bf(a0), h1 = f2bf(a1), h2 = f2bf(a2), h3 = f2bf(a3);
        short l0 = f2bf(a0 - bf2f(h0)), l1 = f2bf(a1 - bf2f(h1));
        short l2 = f2bf(a2 - bf2f(h2)), l3 = f2bf(a3 - bf2f(h3));
        uint2 hw, lw;
        hw.x = (unsigned short)h0 | ((unsigned)(unsigned short)h1 << 16);
        hw.y = (unsigned short)h2 | ((unsigned)(unsigned short)h3 << 16);
        lw.x = (unsigned short)l0 | ((unsigned)(unsigned short)l1 << 16);
        lw.y = (unsigned short)l2 | ((unsigned)(unsigned short)l3 << 16);
        *(uint2*)&LB[(slab * 17 + r) * 8 + i0] = hw;
        *(uint2*)&LB[4352 + (slab * 17 + r) * 8 + i0] = lw;
    }
    __syncthreads();

    // ---- phase 2: 3-term MFMA, wave wv -> cols [wv*64, wv*64+64) ----
    int bcol = wv * 64;
    f32x4 acc2[4] = {};
#pragma unroll
    for (int s = 0; s < 8; ++s) {
        int sl = s * 4 + lg;
        bf16x8 ah = *(bf16x8*)&LB[(sl * 17 + lr) * 8];
        bf16x8 al = *(bf16x8*)&LB[4352 + (sl * 17 + lr) * 8];
        const short* pbh = PBh + ((size_t)sl * 256 + bcol + lr) * 8;
        const short* pbl = PBl + ((size_t)sl * 256 + bcol + lr) * 8;
        bf16x8 bh[4], bl[4];
#pragma unroll
        for (int ni = 0; ni < 4; ni++) {
            bh[ni] = *(const bf16x8*)(pbh + ni * 128);
            bl[ni] = *(const bf16x8*)(pbl + ni * 128);
        }
#pragma unroll
        for (int ni = 0; ni < 4; ni++) {
            acc2[ni] = __builtin_amdgcn_mfma_f32_16x16x32_bf16(ah, bh[ni], acc2[ni], 0, 0, 0);
            acc2[ni] = __builtin_amdgcn_mfma_f32_16x16x32_bf16(ah, bl[ni], acc2[ni], 0, 0, 0);
            acc2[ni] = __builtin_amdgcn_mfma_f32_16x16x32_bf16(al, bh[ni], acc2[ni], 0, 0, 0);
        }
    }
    __syncthreads();   // all LDS A-frag reads done; safe to reuse buffer

    // ---- epilogue: relu(acc+bias) [*dinv] -> stage q-pack tile in LDS ----
    float dvo[4];
    if (SCALE_OUT) {
#pragma unroll
        for (int j = 0; j < 4; j++) {
            int row = brow + lg * 4 + j;
            dvo[j] = (row < n) ? dinv[row] : 0.f;
        }
    }
#pragma unroll
    for (int ni = 0; ni < 4; ni++) {
        int col = bcol + ni * 16 + lr;
        float bv = bias[col];
        int so = (col >> 2) * 8 + (col & 3);
#pragma unroll
        for (int j = 0; j < 4; j++) {
            int r = lg * 4 + j;
            float o = fmaxf(acc2[ni][j] + bv, 0.f);
            if (SCALE_OUT) o *= dvo[j];
            short hh = f2bf(o);
            short hl = f2bf(o - bf2f(hh));
            LB[r * 512 + so] = hh;
            LB[r * 512 + so + 4] = hl;
        }
    }
    __syncthreads();

    // ---- cooperative full-line write-out: 1024 x 16B chunks (1KB/row) ----
#pragma unroll
    for (int q = 0; q < 4; q++) {
        int idx = t + q * 256;          // [0,1024)
        int row = idx >> 6, c = idx & 63;
        int vv = brow + row;
        if (vv < n)
            *(uint4*)(Aout + (size_t)vv * 512 + c * 8) = *(const uint4*)&LB[row * 512 + c * 8];
    }
}

// ---------------- pooling (mean + max over rows) from q-pack ------------------

__global__ __launch_bounds__(256) void pool_packed(const short* __restrict__ P, int n,
                                                   float* __restrict__ pool_sum, int* __restrict__ pool_max) {
    int t = threadIdx.x;
    int so = (t >> 2) * 8 + (t & 3);
    int chunk = (n + gridDim.x - 1) / gridDim.x;
    int r0 = blockIdx.x * chunk, r1 = min(n, r0 + chunk);
    float s = 0.f, mx = 0.f;
    for (int r = r0; r < r1; r++) {
        size_t a = (size_t)r * 512 + so;
        float v = bf2f(P[a]) + bf2f(P[a + 4]);
        s += v;
        mx = fmaxf(mx, v);
    }
    atomicAdd(&pool_sum[t], s);
    atomicMax(&pool_max[t], __float_as_int(mx));
}

// ---------------- final MLP head (single block) ----------------

__global__ __launch_bounds__(256) void mlp_head(const float* __restrict__ pool_sum, const int* __restrict__ pool_max,
                                                const float* __restrict__ Wp1, const float* __restrict__ bp1,
                                                const float* __restrict__ Wp2, const float* __restrict__ bp2,
                                                float* __restrict__ out, float invn) {
    __shared__ float g[2 * HID];
    __shared__ float hid[HID];
    int t = threadIdx.x;
    g[t] = pool_sum[t] * invn;
    g[HID + t] = __int_as_float(pool_max[t]);
    __syncthreads();
    float acc = bp1[t];
#pragma unroll 8
    for (int j = 0; j < 2 * HID; j++) acc = fmaf(g[j], Wp1[j * HID + t], acc);
    hid[t] = fmaxf(acc, 0.f);
    __syncthreads();
    if (t < DEMB) {
        float a2 = bp2[t];
#pragma unroll 8
        for (int j = 0; j < HID; j++) a2 = fmaf(hid[j], Wp2[j * DEMB + t], a2);
        out[t] = a2;
    }
}

// ---------------- launcher ----------------

extern "C" void kernel_launch(void* const* d_in, const int* in_sizes, int n_in,
                              void* d_out, int out_size, void* d_ws, size_t ws_size,
                              hipStream_t stream) {
    const float* x   = (const float*)d_in[0];
    const int*   ei  = (const int*)d_in[1];
    const float* W1  = (const float*)d_in[2];
    const float* b1  = (const float*)d_in[3];
    const float* W2  = (const float*)d_in[4];
    const float* b2  = (const float*)d_in[5];
    const float* Wc  = (const float*)d_in[6];
    const float* bc  = (const float*)d_in[7];
    const float* Wp1 = (const float*)d_in[8];
    const float* bp1 = (const float*)d_in[9];
    const float* Wp2 = (const float*)d_in[10];
    const float* bp2 = (const float*)d_in[11];
    float* out = (float*)d_out;

    int N = in_sizes[0] / FIN;
    int E = in_sizes[1] / 2;
    int gb64 = (N + 63) / 64;
    int nb16 = (N + 15) / 16;
    int R = gb64 * 64;                   // padded rows for packed buffers

    char* base = (char*)d_ws;
    float* tmp  = (float*)base;                          // [N,256] fp32 (enc1->enc2 only)
    short* actB = (short*)base;                          // [R,512] q-pack (aliases tmp)
    short* actA = (short*)(base + (size_t)R * 1024);     // [R,512] q-pack
    int*   counts  = (int*)(base + 2 * (size_t)R * 1024);// [N]
    int*   row_ptr = counts + N;                         // [N+1]
    int*   cursor  = row_ptr + (N + 1);                  // [N]
    int*   adj     = cursor + N;                         // [E]
    float* dinvp   = (float*)(adj + E);                  // [N]
    float* pool_sum = dinvp + N;                         // [HID]
    int*   pool_max = (int*)(pool_sum + HID);            // [HID]
    int*   chunkSums = pool_max + HID;                   // [<=64]
    short* PH = (short*)((((uintptr_t)(chunkSums + 64)) + 15) & ~(uintptr_t)15);
    short* PL = PH + 278528;
    const int oW1 = 0, oW2 = 16384, oC0 = 81920, oC1 = 147456, oC2 = 212992;

    int nch = (N + 1023) / 1024;
    int nb256 = (N + 255) / 256;
    int eb256 = (E + 255) / 256;

    zero_kernel<<<nb256, 256, 0, stream>>>(counts, N, pool_sum, pool_max);
    hist_kernel<<<eb256, 256, 0, stream>>>(ei, E, counts);
    scan_partial<<<nch, 256, 0, stream>>>(counts, N, chunkSums, dinvp);
    scan_sums<<<1, 64, 0, stream>>>(chunkSums, nch);
    scan_final<<<nch, 256, 0, stream>>>(counts, N, chunkSums, row_ptr, cursor);
    fill_kernel<<<eb256, 256, 0, stream>>>(ei, E, cursor, adj);

    pack_all<<<64 + 4 * 256, 256, 0, stream>>>(W1, W2, Wc, PH, PL);

    // encoder: tmp = relu(x@W1+b1); actA = qpack(dinv * (tmp@W2+b2))
    gemm_conv<FIN, true, true, false, false><<<gb64, 256, 0, stream>>>(x, PH + oW1, PL + oW1, b1, tmp, nullptr, nullptr, N);
    gemm_conv<HID, false, true, true, true><<<gb64, 256, 0, stream>>>(tmp, PH + oW2, PL + oW2, b2, nullptr, actA, dinvp, N);

    // fused GCN layers: out = relu((S@h)@Wc + bc); pre-scaled except last
    layer_fused<true><<<nb16, 256, 0, stream>>>(actA, row_ptr, adj, dinvp, PH + oC0, PL + oC0, bc + 0 * HID, actB, N);
    layer_fused<true><<<nb16, 256, 0, stream>>>(actB, row_ptr, adj, dinvp, PH + oC1, PL + oC1, bc + 1 * HID, actA, N);
    layer_fused<false><<<nb16, 256, 0, stream>>>(actA, row_ptr, adj, dinvp, PH + oC2, PL + oC2, bc + 2 * HID, actB, N);

    // pooling + head
    pool_packed<<<256, 256, 0, stream>>>(actB, N, pool_sum, pool_max);
    mlp_head<<<1, 256, 0, stream>>>(pool_sum, pool_max, Wp1, bp1, Wp2, bp2, out, 1.0f / (float)N);
}

// Round 10
// 639.294 us; speedup vs baseline: 1.1393x; 1.1393x over previous
//
#include <hip/hip_runtime.h>

#define FIN 64
#define HID 256
#define DEMB 128
#define NLAYERS 3

typedef __attribute__((ext_vector_type(8))) short bf16x8;
typedef __attribute__((ext_vector_type(4))) float f32x4;

__device__ inline short f2bf(float x) {               // RNE fp32 -> bf16 bits
    unsigned u = __float_as_uint(x);
    u += 0x7fff + ((u >> 16) & 1);
    return (short)(u >> 16);
}
__device__ inline float bf2f(short h) {
    return __uint_as_float(((unsigned)(unsigned short)h) << 16);
}

// Activation layout "rowpack": per row r, 512 shorts (1KB contiguous):
//   h of col c at r*512 + (c>>3)*8 + (c&7);  l at +256 shorts.
// Values PRE-SCALED by dinv[row] except after the last layer.

// add h+l recon of 4 cols held as uint2 pair (H=h bits, L=l bits) into acc
#define RECON2(H, L) do { \
    acc.x += __uint_as_float((H).x << 16) + __uint_as_float((L).x << 16); \
    acc.y += __uint_as_float((H).x & 0xffff0000u) + __uint_as_float((L).x & 0xffff0000u); \
    acc.z += __uint_as_float((H).y << 16) + __uint_as_float((L).y << 16); \
    acc.w += __uint_as_float((H).y & 0xffff0000u) + __uint_as_float((L).y & 0xffff0000u); } while (0)

__device__ inline void split2(float a0, float a1, float a2, float a3, uint2& hw, uint2& lw) {
    short h0 = f2bf(a0), h1 = f2bf(a1), h2 = f2bf(a2), h3 = f2bf(a3);
    short l0 = f2bf(a0 - bf2f(h0)), l1 = f2bf(a1 - bf2f(h1));
    short l2 = f2bf(a2 - bf2f(h2)), l3 = f2bf(a3 - bf2f(h3));
    hw.x = (unsigned short)h0 | ((unsigned)(unsigned short)h1 << 16);
    hw.y = (unsigned short)h2 | ((unsigned)(unsigned short)h3 << 16);
    lw.x = (unsigned short)l0 | ((unsigned)(unsigned short)l1 << 16);
    lw.y = (unsigned short)l2 | ((unsigned)(unsigned short)l3 << 16);
}

// ---------------- small graph-prep kernels ----------------

__global__ __launch_bounds__(256) void zero_kernel(int* counts, int n, float* pool_sum, int* pool_max) {
    int i = blockIdx.x * 256 + threadIdx.x;
    if (i < n) counts[i] = 0;
    if (i < HID) { pool_sum[i] = 0.0f; pool_max[i] = 0; }
}

__global__ __launch_bounds__(256) void hist_kernel(const int* __restrict__ ei, int E, int* __restrict__ counts) {
    int e = blockIdx.x * 256 + threadIdx.x;
    if (e < E) atomicAdd(&counts[ei[E + e]], 1);
}

__global__ __launch_bounds__(256) void scan_partial(const int* __restrict__ counts, int n,
                                                    int* __restrict__ chunkSums, float* __restrict__ dinv) {
    __shared__ int s[256];
    int t = threadIdx.x, base = blockIdx.x * 1024;
    int sum = 0;
#pragma unroll
    for (int j = 0; j < 4; j++) {
        int i = base + t * 4 + j;
        if (i < n) {
            int c = counts[i];
            sum += c;
            dinv[i] = rsqrtf((float)(c + 1));
        }
    }
    s[t] = sum; __syncthreads();
    for (int off = 128; off > 0; off >>= 1) { if (t < off) s[t] += s[t + off]; __syncthreads(); }
    if (t == 0) chunkSums[blockIdx.x] = s[0];
}

__global__ void scan_sums(int* cs, int nch) {
    int l = threadIdx.x;
    int orig = (l < nch) ? cs[l] : 0;
    int v = orig;
    for (int off = 1; off < 64; off <<= 1) {
        int x = __shfl_up(v, off, 64);
        if (l >= off) v += x;
    }
    if (l < nch) cs[l] = v - orig;
}

__global__ __launch_bounds__(256) void scan_final(const int* __restrict__ counts, int n,
                                                  const int* __restrict__ chunkOff, int* __restrict__ row_ptr,
                                                  int* __restrict__ cursor) {
    __shared__ int s[256];
    int t = threadIdx.x, base = blockIdx.x * 1024;
    int v[4]; int sum = 0;
#pragma unroll
    for (int j = 0; j < 4; j++) { int i = base + t * 4 + j; v[j] = (i < n) ? counts[i] : 0; sum += v[j]; }
    s[t] = sum; __syncthreads();
    for (int off = 1; off < 256; off <<= 1) {
        int x = (t >= off) ? s[t - off] : 0;
        __syncthreads();
        s[t] += x;
        __syncthreads();
    }
    int run = chunkOff[blockIdx.x] + (s[t] - sum);
#pragma unroll
    for (int j = 0; j < 4; j++) {
        int i = base + t * 4 + j;
        if (i < n) {
            row_ptr[i] = run; cursor[i] = run; run += v[j];
            if (i == n - 1) row_ptr[n] = run;
        }
    }
}

__global__ __launch_bounds__(256) void fill_kernel(const int* __restrict__ ei, int E,
                                                   int* __restrict__ cursor, int* __restrict__ adj) {
    int e = blockIdx.x * 256 + threadIdx.x;
    if (e < E) {
        int s = ei[e], d = ei[E + e];
        int p = atomicAdd(&cursor[d], 1);
        adj[p] = s;
    }
}

// ---------------- weight packing (slab-major) ----------------

__global__ __launch_bounds__(256) void pack_all(const float* __restrict__ W1, const float* __restrict__ W2,
                                                const float* __restrict__ Wc,
                                                short* __restrict__ PH, short* __restrict__ PL) {
    int b = blockIdx.x, n = threadIdx.x;
    const float* src; int k; size_t dst;
    if (b < 64) { src = W1; k = b; dst = 0; }
    else {
        int m = (b - 64) >> 8; k = (b - 64) & 255;
        src = (m == 0) ? W2 : (Wc + (size_t)(m - 1) * 65536);
        dst = 16384 + (size_t)m * 65536;
    }
    float w = src[(size_t)k * 256 + n];
    short h = f2bf(w);
    short l = f2bf(w - bf2f(h));
    int o = ((k >> 3) * 256 + n) * 8 + (k & 7);
    PH[dst + o] = h; PL[dst + o] = l;
}

// ---------------- fused encoder: out = qpack(dinv * (relu(x@W1+b1)@W2 + b2)) --
// BM=32 rows/block, 4 waves (wave w -> cols [64w,64w+64) in both stages).
// LDS aliased region LB[16896] shorts (33792 B):
//   stage1 frags: Ah1 at 0 ([8][33][8]=2112 sh), Al1 at 2112
//   t frags:      tAh at 0 ([32][33][8]=8448 sh), tAl at 8448
//   epilogue:     rowpack tile [32][512] = 16384 sh

__global__ __launch_bounds__(256) void encoder_fused(const float* __restrict__ x,
                                                     const short* __restrict__ PB1h, const short* __restrict__ PB1l,
                                                     const short* __restrict__ PB2h, const short* __restrict__ PB2l,
                                                     const float* __restrict__ b1, const float* __restrict__ b2,
                                                     const float* __restrict__ dinv,
                                                     short* __restrict__ Aout, int n) {
    __shared__ short LB[16896];
    int t = threadIdx.x, lane = t & 63, wv = t >> 6;
    int lr = lane & 15, lg = lane >> 4;
    int brow = blockIdx.x * 32;
    int bcol = wv * 64;

    // ---- stage 1 load: x tile 32x64 -> split-bf16 A frags ----
#pragma unroll
    for (int l = 0; l < 2; l++) {
        int lin = t + l * 256;               // 0..511 float4s
        int r = lin >> 4, kq = (lin & 15) * 4;
        int row = brow + r;
        float4 v = (row < n) ? *(const float4*)(x + (size_t)row * FIN + kq)
                             : make_float4(0.f, 0.f, 0.f, 0.f);
        uint2 hw, lw; split2(v.x, v.y, v.z, v.w, hw, lw);
        int g = kq >> 3, i0 = kq & 7;
        *(uint2*)&LB[(g * 33 + r) * 8 + i0] = hw;
        *(uint2*)&LB[2112 + (g * 33 + r) * 8 + i0] = lw;
    }
    __syncthreads();

    // ---- stage 1 MFMA: t = x@W1 (+b1, relu later), K=64 ----
    f32x4 acc1[2][4] = {};
#pragma unroll
    for (int s = 0; s < 2; s++) {
        int sl = s * 4 + lg;
        bf16x8 ah[2], al[2], bh[4], bl[4];
#pragma unroll
        for (int mi = 0; mi < 2; mi++) {
            ah[mi] = *(bf16x8*)&LB[(sl * 33 + mi * 16 + lr) * 8];
            al[mi] = *(bf16x8*)&LB[2112 + (sl * 33 + mi * 16 + lr) * 8];
        }
        const short* pbh = PB1h + ((size_t)sl * 256 + bcol + lr) * 8;
        const short* pbl = PB1l + ((size_t)sl * 256 + bcol + lr) * 8;
#pragma unroll
        for (int ni = 0; ni < 4; ni++) {
            bh[ni] = *(const bf16x8*)(pbh + ni * 128);
            bl[ni] = *(const bf16x8*)(pbl + ni * 128);
        }
#pragma unroll
        for (int mi = 0; mi < 2; mi++)
#pragma unroll
            for (int ni = 0; ni < 4; ni++) {
                acc1[mi][ni] = __builtin_amdgcn_mfma_f32_16x16x32_bf16(ah[mi], bh[ni], acc1[mi][ni], 0, 0, 0);
                acc1[mi][ni] = __builtin_amdgcn_mfma_f32_16x16x32_bf16(ah[mi], bl[ni], acc1[mi][ni], 0, 0, 0);
                acc1[mi][ni] = __builtin_amdgcn_mfma_f32_16x16x32_bf16(al[mi], bh[ni], acc1[mi][ni], 0, 0, 0);
            }
    }
    __syncthreads();   // stage-1 frag reads done; LB reusable

    // ---- t = relu(acc1 + b1) -> split-bf16 t-frags in LDS ----
#pragma unroll
    for (int ni = 0; ni < 4; ni++) {
        int col = bcol + ni * 16 + lr;
        float bv = b1[col];
        int sl2 = col >> 3, i = col & 7;
#pragma unroll
        for (int mi = 0; mi < 2; mi++)
#pragma unroll
            for (int j = 0; j < 4; j++) {
                int r = mi * 16 + lg * 4 + j;
                float o = fmaxf(acc1[mi][ni][j] + bv, 0.f);
                short hh = f2bf(o);
                short hl = f2bf(o - bf2f(hh));
                LB[(sl2 * 33 + r) * 8 + i] = hh;
                LB[8448 + (sl2 * 33 + r) * 8 + i] = hl;
            }
    }
    __syncthreads();

    // ---- stage 2 MFMA: out = t@W2, K=256 ----
    f32x4 acc2[2][4] = {};
#pragma unroll
    for (int s = 0; s < 8; s++) {
        int sl = s * 4 + lg;
        bf16x8 ah[2], al[2], bh[4], bl[4];
#pragma unroll
        for (int mi = 0; mi < 2; mi++) {
            ah[mi] = *(bf16x8*)&LB[(sl * 33 + mi * 16 + lr) * 8];
            al[mi] = *(bf16x8*)&LB[8448 + (sl * 33 + mi * 16 + lr) * 8];
        }
        const short* pbh = PB2h + ((size_t)sl * 256 + bcol + lr) * 8;
        const short* pbl = PB2l + ((size_t)sl * 256 + bcol + lr) * 8;
#pragma unroll
        for (int ni = 0; ni < 4; ni++) {
            bh[ni] = *(const bf16x8*)(pbh + ni * 128);
            bl[ni] = *(const bf16x8*)(pbl + ni * 128);
        }
#pragma unroll
        for (int mi = 0; mi < 2; mi++)
#pragma unroll
            for (int ni = 0; ni < 4; ni++) {
                acc2[mi][ni] = __builtin_amdgcn_mfma_f32_16x16x32_bf16(ah[mi], bh[ni], acc2[mi][ni], 0, 0, 0);
                acc2[mi][ni] = __builtin_amdgcn_mfma_f32_16x16x32_bf16(ah[mi], bl[ni], acc2[mi][ni], 0, 0, 0);
                acc2[mi][ni] = __builtin_amdgcn_mfma_f32_16x16x32_bf16(al[mi], bh[ni], acc2[mi][ni], 0, 0, 0);
            }
    }
    __syncthreads();   // t-frag reads done; LB reusable

    // ---- epilogue: dinv * (acc2 + b2) -> rowpack tile in LDS ----
    float dvo[2][4];
#pragma unroll
    for (int mi = 0; mi < 2; mi++)
#pragma unroll
        for (int j = 0; j < 4; j++) {
            int row = brow + mi * 16 + lg * 4 + j;
            dvo[mi][j] = (row < n) ? dinv[row] : 0.f;
        }
#pragma unroll
    for (int ni = 0; ni < 4; ni++) {
        int col = bcol + ni * 16 + lr;
        float bv = b2[col];
        int so = (col >> 3) * 8 + (col & 7);
#pragma unroll
        for (int mi = 0; mi < 2; mi++)
#pragma unroll
            for (int j = 0; j < 4; j++) {
                int r = mi * 16 + lg * 4 + j;
                float o = (acc2[mi][ni][j] + bv) * dvo[mi][j];
                short hh = f2bf(o);
                short hl = f2bf(o - bf2f(hh));
                LB[r * 512 + so] = hh;
                LB[r * 512 + 256 + so] = hl;
            }
    }
    __syncthreads();

    // ---- cooperative full-line write-out: 2048 x 16B chunks ----
#pragma unroll
    for (int q = 0; q < 8; q++) {
        int idx = t + q * 256;          // [0,2048)
        int row = idx >> 6, c = idx & 63;
        int vv = brow + row;
        if (vv < n)
            *(uint4*)(Aout + (size_t)vv * 512 + c * 8) = *(const uint4*)&LB[row * 512 + c * 8];
    }
}

// ---------------- fused GCN layer: out = relu((S@h)@Wc + b) -------------------
// Input rowpack PRE-SCALED by dinv => gather is a pure sum (R8 access pattern).
// BM=16 rows/block, 4 waves. LDS aliased: A-frags (8704 sh) / out tile (8192 sh).
// SCALE_OUT: multiply output by dinv[row] (all but last layer).

template<bool SCALE_OUT>
__global__ __launch_bounds__(256) void layer_fused(const short* __restrict__ Ain,
                                                   const int* __restrict__ row_ptr, const int* __restrict__ adj,
                                                   const float* __restrict__ dinv,
                                                   const short* __restrict__ PBh, const short* __restrict__ PBl,
                                                   const float* __restrict__ bias,
                                                   short* __restrict__ Aout, int n) {
    __shared__ short LB[8704];
    int t = threadIdx.x, lane = t & 63, wv = t >> 6;
    int lr = lane & 15, lg = lane >> 4;
    int brow = blockIdx.x * 16;
    int slab = lane >> 1, i0 = (lane & 1) * 4;
    int loff = slab * 8 + i0;                       // h byte-chunk within row

    // ---- phase 1: gather + sum (each wave: 4 dst rows; 4-deep, 2x8B loads) ----
    for (int it = 0; it < 4; ++it) {
        int r = wv * 4 + it, v = brow + r;
        if (v >= n) break;                          // wave-uniform
        float dv = dinv[v];
        size_t vb = (size_t)v * 512 + loff;
        uint2 H0 = *(const uint2*)(Ain + vb);
        uint2 L0 = *(const uint2*)(Ain + vb + 256);
        float4 acc = make_float4(0.f, 0.f, 0.f, 0.f);
        RECON2(H0, L0);
        int e = row_ptr[v], end = row_ptr[v + 1];
        for (; e + 4 <= end; e += 4) {
            int s4[4]; uint2 Hh[4], Ll[4];
#pragma unroll
            for (int j = 0; j < 4; j++) s4[j] = adj[e + j];
#pragma unroll
            for (int j = 0; j < 4; j++) {
                size_t b = (size_t)s4[j] * 512 + loff;
                Hh[j] = *(const uint2*)(Ain + b);
                Ll[j] = *(const uint2*)(Ain + b + 256);
            }
#pragma unroll
            for (int j = 0; j < 4; j++) RECON2(Hh[j], Ll[j]);
        }
        for (; e < end; e++) {
            size_t b = (size_t)adj[e] * 512 + loff;
            uint2 Hh = *(const uint2*)(Ain + b);
            uint2 Ll = *(const uint2*)(Ain + b + 256);
            RECON2(Hh, Ll);
        }
        uint2 hw, lw;
        split2(dv * acc.x, dv * acc.y, dv * acc.z, dv * acc.w, hw, lw);
        *(uint2*)&LB[(slab * 17 + r) * 8 + i0] = hw;
        *(uint2*)&LB[4352 + (slab * 17 + r) * 8 + i0] = lw;
    }
    __syncthreads();

    // ---- phase 2: 3-term MFMA, wave wv -> cols [wv*64, wv*64+64) ----
    int bcol = wv * 64;
    f32x4 acc2[4] = {};
#pragma unroll
    for (int s = 0; s < 8; ++s) {
        int sl = s * 4 + lg;
        bf16x8 ah = *(bf16x8*)&LB[(sl * 17 + lr) * 8];
        bf16x8 al = *(bf16x8*)&LB[4352 + (sl * 17 + lr) * 8];
        const short* pbh = PBh + ((size_t)sl * 256 + bcol + lr) * 8;
        const short* pbl = PBl + ((size_t)sl * 256 + bcol + lr) * 8;
        bf16x8 bh[4], bl[4];
#pragma unroll
        for (int ni = 0; ni < 4; ni++) {
            bh[ni] = *(const bf16x8*)(pbh + ni * 128);
            bl[ni] = *(const bf16x8*)(pbl + ni * 128);
        }
#pragma unroll
        for (int ni = 0; ni < 4; ni++) {
            acc2[ni] = __builtin_amdgcn_mfma_f32_16x16x32_bf16(ah, bh[ni], acc2[ni], 0, 0, 0);
            acc2[ni] = __builtin_amdgcn_mfma_f32_16x16x32_bf16(ah, bl[ni], acc2[ni], 0, 0, 0);
            acc2[ni] = __builtin_amdgcn_mfma_f32_16x16x32_bf16(al, bh[ni], acc2[ni], 0, 0, 0);
        }
    }
    __syncthreads();   // all LDS A-frag reads done; safe to reuse buffer

    // ---- epilogue: relu(acc+bias) [*dinv] -> stage rowpack tile in LDS ----
    float dvo[4];
    if (SCALE_OUT) {
#pragma unroll
        for (int j = 0; j < 4; j++) {
            int row = brow + lg * 4 + j;
            dvo[j] = (row < n) ? dinv[row] : 0.f;
        }
    }
#pragma unroll
    for (int ni = 0; ni < 4; ni++) {
        int col = bcol + ni * 16 + lr;
        float bv = bias[col];
        int so = (col >> 3) * 8 + (col & 7);
#pragma unroll
        for (int j = 0; j < 4; j++) {
            int r = lg * 4 + j;
            float o = fmaxf(acc2[ni][j] + bv, 0.f);
            if (SCALE_OUT) o *= dvo[j];
            short hh = f2bf(o);
            short hl = f2bf(o - bf2f(hh));
            LB[r * 256 + so] = hh;
            LB[4096 + r * 256 + so] = hl;
        }
    }
    __syncthreads();

    // ---- cooperative full-line write-out: 1024 x 16B chunks ----
#pragma unroll
    for (int q = 0; q < 4; q++) {
        int idx = t + q * 256;          // [0,1024)
        int row = idx >> 6, c = idx & 63;
        int vv = brow + row;
        if (vv < n) {
            const short* src;
            short* dst;
            if (c < 32) { src = &LB[row * 256 + c * 8];              dst = Aout + (size_t)vv * 512 + c * 8; }
            else        { src = &LB[4096 + row * 256 + (c - 32) * 8]; dst = Aout + (size_t)vv * 512 + 256 + (c - 32) * 8; }
            *(uint4*)dst = *(const uint4*)src;
        }
    }
}

// ---------------- pooling (mean + max over rows) from rowpack -----------------

__global__ __launch_bounds__(256) void pool_packed(const short* __restrict__ P, int n,
                                                   float* __restrict__ pool_sum, int* __restrict__ pool_max) {
    int t = threadIdx.x;
    int so = (t >> 3) * 8 + (t & 7);
    int chunk = (n + gridDim.x - 1) / gridDim.x;
    int r0 = blockIdx.x * chunk, r1 = min(n, r0 + chunk);
    float s = 0.f, mx = 0.f;
    for (int r = r0; r < r1; r++) {
        size_t a = (size_t)r * 512 + so;
        float v = bf2f(P[a]) + bf2f(P[a + 256]);
        s += v;
        mx = fmaxf(mx, v);
    }
    atomicAdd(&pool_sum[t], s);
    atomicMax(&pool_max[t], __float_as_int(mx));
}

// ---------------- final MLP head (single block) ----------------

__global__ __launch_bounds__(256) void mlp_head(const float* __restrict__ pool_sum, const int* __restrict__ pool_max,
                                                const float* __restrict__ Wp1, const float* __restrict__ bp1,
                                                const float* __restrict__ Wp2, const float* __restrict__ bp2,
                                                float* __restrict__ out, float invn) {
    __shared__ float g[2 * HID];
    __shared__ float hid[HID];
    int t = threadIdx.x;
    g[t] = pool_sum[t] * invn;
    g[HID + t] = __int_as_float(pool_max[t]);
    __syncthreads();
    float acc = bp1[t];
#pragma unroll 8
    for (int j = 0; j < 2 * HID; j++) acc = fmaf(g[j], Wp1[j * HID + t], acc);
    hid[t] = fmaxf(acc, 0.f);
    __syncthreads();
    if (t < DEMB) {
        float a2 = bp2[t];
#pragma unroll 8
        for (int j = 0; j < HID; j++) a2 = fmaf(hid[j], Wp2[j * DEMB + t], a2);
        out[t] = a2;
    }
}

// ---------------- launcher ----------------

extern "C" void kernel_launch(void* const* d_in, const int* in_sizes, int n_in,
                              void* d_out, int out_size, void* d_ws, size_t ws_size,
                              hipStream_t stream) {
    const float* x   = (const float*)d_in[0];
    const int*   ei  = (const int*)d_in[1];
    const float* W1  = (const float*)d_in[2];
    const float* b1  = (const float*)d_in[3];
    const float* W2  = (const float*)d_in[4];
    const float* b2  = (const float*)d_in[5];
    const float* Wc  = (const float*)d_in[6];
    const float* bc  = (const float*)d_in[7];
    const float* Wp1 = (const float*)d_in[8];
    const float* bp1 = (const float*)d_in[9];
    const float* Wp2 = (const float*)d_in[10];
    const float* bp2 = (const float*)d_in[11];
    float* out = (float*)d_out;

    int N = in_sizes[0] / FIN;
    int E = in_sizes[1] / 2;
    int nb32 = (N + 31) / 32;
    int nb16 = (N + 15) / 16;
    int R = nb32 * 32;                   // padded rows for packed buffers

    char* base = (char*)d_ws;
    short* actA = (short*)base;                          // [R,512] rowpack
    short* actB = (short*)(base + (size_t)R * 1024);     // [R,512] rowpack
    int*   counts  = (int*)(base + 2 * (size_t)R * 1024);// [N]
    int*   row_ptr = counts + N;                         // [N+1]
    int*   cursor  = row_ptr + (N + 1);                  // [N]
    int*   adj     = cursor + N;                         // [E]
    float* dinvp   = (float*)(adj + E);                  // [N]
    float* pool_sum = dinvp + N;                         // [HID]
    int*   pool_max = (int*)(pool_sum + HID);            // [HID]
    int*   chunkSums = pool_max + HID;                   // [<=64]
    short* PH = (short*)((((uintptr_t)(chunkSums + 64)) + 15) & ~(uintptr_t)15);
    short* PL = PH + 278528;
    const int oW1 = 0, oW2 = 16384, oC0 = 81920, oC1 = 147456, oC2 = 212992;

    int nch = (N + 1023) / 1024;
    int nb256 = (N + 255) / 256;
    int eb256 = (E + 255) / 256;

    zero_kernel<<<nb256, 256, 0, stream>>>(counts, N, pool_sum, pool_max);
    hist_kernel<<<eb256, 256, 0, stream>>>(ei, E, counts);
    scan_partial<<<nch, 256, 0, stream>>>(counts, N, chunkSums, dinvp);
    scan_sums<<<1, 64, 0, stream>>>(chunkSums, nch);
    scan_final<<<nch, 256, 0, stream>>>(counts, N, chunkSums, row_ptr, cursor);
    fill_kernel<<<eb256, 256, 0, stream>>>(ei, E, cursor, adj);

    pack_all<<<64 + 4 * 256, 256, 0, stream>>>(W1, W2, Wc, PH, PL);

    // fused encoder: actA = rowpack(dinv * (relu(x@W1+b1)@W2 + b2))
    encoder_fused<<<nb32, 256, 0, stream>>>(x, PH + oW1, PL + oW1, PH + oW2, PL + oW2,
                                            b1, b2, dinvp, actA, N);

    // fused GCN layers: out = relu((S@h)@Wc + bc); pre-scaled except last
    layer_fused<true><<<nb16, 256, 0, stream>>>(actA, row_ptr, adj, dinvp, PH + oC0, PL + oC0, bc + 0 * HID, actB, N);
    layer_fused<true><<<nb16, 256, 0, stream>>>(actB, row_ptr, adj, dinvp, PH + oC1, PL + oC1, bc + 1 * HID, actA, N);
    layer_fused<false><<<nb16, 256, 0, stream>>>(actA, row_ptr, adj, dinvp, PH + oC2, PL + oC2, bc + 2 * HID, actB, N);

    // pooling + head
    pool_packed<<<256, 256, 0, stream>>>(actB, N, pool_sum, pool_max);
    mlp_head<<<1, 256, 0, stream>>>(pool_sum, pool_max, Wp1, bp1, Wp2, bp2, out, 1.0f / (float)N);
}

// Round 11
// 481.190 us; speedup vs baseline: 1.5136x; 1.3286x over previous
//
#include <hip/hip_runtime.h>
#include <hip/hip_fp16.h>

#define FIN 64
#define HID 256
#define DEMB 128
#define NLAYERS 3

typedef __attribute__((ext_vector_type(8))) short bf16x8;
typedef __attribute__((ext_vector_type(4))) float f32x4;

__device__ inline short f2bf(float x) {               // RNE fp32 -> bf16 bits
    unsigned u = __float_as_uint(x);
    u += 0x7fff + ((u >> 16) & 1);
    return (short)(u >> 16);
}
__device__ inline float bf2f(short h) {
    return __uint_as_float(((unsigned)(unsigned short)h) << 16);
}

// Activation layout "hpack": per row r, 256 fp16 (512B contiguous), linear cols.
// Values PRE-SCALED by dinv[row] except after the last layer.

// add 4 fp16 cols (uint2) into fp32 acc
#define HADD(V) do { \
    __half2 p0 = *(__half2*)&(V).x, p1 = *(__half2*)&(V).y; \
    float2 f0 = __half22float2(p0), f1 = __half22float2(p1); \
    acc.x += f0.x; acc.y += f0.y; acc.z += f1.x; acc.w += f1.y; } while (0)

__device__ inline void split2(float a0, float a1, float a2, float a3, uint2& hw, uint2& lw) {
    short h0 = f2bf(a0), h1 = f2bf(a1), h2 = f2bf(a2), h3 = f2bf(a3);
    short l0 = f2bf(a0 - bf2f(h0)), l1 = f2bf(a1 - bf2f(h1));
    short l2 = f2bf(a2 - bf2f(h2)), l3 = f2bf(a3 - bf2f(h3));
    hw.x = (unsigned short)h0 | ((unsigned)(unsigned short)h1 << 16);
    hw.y = (unsigned short)h2 | ((unsigned)(unsigned short)h3 << 16);
    lw.x = (unsigned short)l0 | ((unsigned)(unsigned short)l1 << 16);
    lw.y = (unsigned short)l2 | ((unsigned)(unsigned short)l3 << 16);
}

// ---------------- small graph-prep kernels ----------------

__global__ __launch_bounds__(256) void zero_kernel(int* counts, int n, float* pool_sum, int* pool_max) {
    int i = blockIdx.x * 256 + threadIdx.x;
    if (i < n) counts[i] = 0;
    if (i < HID) { pool_sum[i] = 0.0f; pool_max[i] = 0; }
}

__global__ __launch_bounds__(256) void hist_kernel(const int* __restrict__ ei, int E, int* __restrict__ counts) {
    int e = blockIdx.x * 256 + threadIdx.x;
    if (e < E) atomicAdd(&counts[ei[E + e]], 1);
}

__global__ __launch_bounds__(256) void scan_partial(const int* __restrict__ counts, int n,
                                                    int* __restrict__ chunkSums, float* __restrict__ dinv) {
    __shared__ int s[256];
    int t = threadIdx.x, base = blockIdx.x * 1024;
    int sum = 0;
#pragma unroll
    for (int j = 0; j < 4; j++) {
        int i = base + t * 4 + j;
        if (i < n) {
            int c = counts[i];
            sum += c;
            dinv[i] = rsqrtf((float)(c + 1));
        }
    }
    s[t] = sum; __syncthreads();
    for (int off = 128; off > 0; off >>= 1) { if (t < off) s[t] += s[t + off]; __syncthreads(); }
    if (t == 0) chunkSums[blockIdx.x] = s[0];
}

__global__ void scan_sums(int* cs, int nch) {
    int l = threadIdx.x;
    int orig = (l < nch) ? cs[l] : 0;
    int v = orig;
    for (int off = 1; off < 64; off <<= 1) {
        int x = __shfl_up(v, off, 64);
        if (l >= off) v += x;
    }
    if (l < nch) cs[l] = v - orig;
}

__global__ __launch_bounds__(256) void scan_final(const int* __restrict__ counts, int n,
                                                  const int* __restrict__ chunkOff, int* __restrict__ row_ptr,
                                                  int* __restrict__ cursor) {
    __shared__ int s[256];
    int t = threadIdx.x, base = blockIdx.x * 1024;
    int v[4]; int sum = 0;
#pragma unroll
    for (int j = 0; j < 4; j++) { int i = base + t * 4 + j; v[j] = (i < n) ? counts[i] : 0; sum += v[j]; }
    s[t] = sum; __syncthreads();
    for (int off = 1; off < 256; off <<= 1) {
        int x = (t >= off) ? s[t - off] : 0;
        __syncthreads();
        s[t] += x;
        __syncthreads();
    }
    int run = chunkOff[blockIdx.x] + (s[t] - sum);
#pragma unroll
    for (int j = 0; j < 4; j++) {
        int i = base + t * 4 + j;
        if (i < n) {
            row_ptr[i] = run; cursor[i] = run; run += v[j];
            if (i == n - 1) row_ptr[n] = run;
        }
    }
}

__global__ __launch_bounds__(256) void fill_kernel(const int* __restrict__ ei, int E,
                                                   int* __restrict__ cursor, int* __restrict__ adj) {
    int e = blockIdx.x * 256 + threadIdx.x;
    if (e < E) {
        int s = ei[e], d = ei[E + e];
        int p = atomicAdd(&cursor[d], 1);
        adj[p] = s;
    }
}

// ---------------- weight packing (slab-major bf16 split) ----------------

__global__ __launch_bounds__(256) void pack_all(const float* __restrict__ W1, const float* __restrict__ W2,
                                                const float* __restrict__ Wc,
                                                short* __restrict__ PH, short* __restrict__ PL) {
    int b = blockIdx.x, n = threadIdx.x;
    const float* src; int k; size_t dst;
    if (b < 64) { src = W1; k = b; dst = 0; }
    else {
        int m = (b - 64) >> 8; k = (b - 64) & 255;
        src = (m == 0) ? W2 : (Wc + (size_t)(m - 1) * 65536);
        dst = 16384 + (size_t)m * 65536;
    }
    float w = src[(size_t)k * 256 + n];
    short h = f2bf(w);
    short l = f2bf(w - bf2f(h));
    int o = ((k >> 3) * 256 + n) * 8 + (k & 7);
    PH[dst + o] = h; PL[dst + o] = l;
}

// ---------------- fused encoder: out = hpack(dinv * (relu(x@W1+b1)@W2 + b2)) --
// BM=32 rows/block, 4 waves. LDS aliased LB[16896] shorts.

__global__ __launch_bounds__(256) void encoder_fused(const float* __restrict__ x,
                                                     const short* __restrict__ PB1h, const short* __restrict__ PB1l,
                                                     const short* __restrict__ PB2h, const short* __restrict__ PB2l,
                                                     const float* __restrict__ b1, const float* __restrict__ b2,
                                                     const float* __restrict__ dinv,
                                                     short* __restrict__ Aout, int n) {
    __shared__ short LB[16896];
    int t = threadIdx.x, lane = t & 63, wv = t >> 6;
    int lr = lane & 15, lg = lane >> 4;
    int brow = blockIdx.x * 32;
    int bcol = wv * 64;

    // ---- stage 1 load: x tile 32x64 -> split-bf16 A frags ----
#pragma unroll
    for (int l = 0; l < 2; l++) {
        int lin = t + l * 256;
        int r = lin >> 4, kq = (lin & 15) * 4;
        int row = brow + r;
        float4 v = (row < n) ? *(const float4*)(x + (size_t)row * FIN + kq)
                             : make_float4(0.f, 0.f, 0.f, 0.f);
        uint2 hw, lw; split2(v.x, v.y, v.z, v.w, hw, lw);
        int g = kq >> 3, i0 = kq & 7;
        *(uint2*)&LB[(g * 33 + r) * 8 + i0] = hw;
        *(uint2*)&LB[2112 + (g * 33 + r) * 8 + i0] = lw;
    }
    __syncthreads();

    // ---- stage 1 MFMA: t = x@W1, K=64 ----
    f32x4 acc1[2][4] = {};
#pragma unroll
    for (int s = 0; s < 2; s++) {
        int sl = s * 4 + lg;
        bf16x8 ah[2], al[2], bh[4], bl[4];
#pragma unroll
        for (int mi = 0; mi < 2; mi++) {
            ah[mi] = *(bf16x8*)&LB[(sl * 33 + mi * 16 + lr) * 8];
            al[mi] = *(bf16x8*)&LB[2112 + (sl * 33 + mi * 16 + lr) * 8];
        }
        const short* pbh = PB1h + ((size_t)sl * 256 + bcol + lr) * 8;
        const short* pbl = PB1l + ((size_t)sl * 256 + bcol + lr) * 8;
#pragma unroll
        for (int ni = 0; ni < 4; ni++) {
            bh[ni] = *(const bf16x8*)(pbh + ni * 128);
            bl[ni] = *(const bf16x8*)(pbl + ni * 128);
        }
#pragma unroll
        for (int mi = 0; mi < 2; mi++)
#pragma unroll
            for (int ni = 0; ni < 4; ni++) {
                acc1[mi][ni] = __builtin_amdgcn_mfma_f32_16x16x32_bf16(ah[mi], bh[ni], acc1[mi][ni], 0, 0, 0);
                acc1[mi][ni] = __builtin_amdgcn_mfma_f32_16x16x32_bf16(ah[mi], bl[ni], acc1[mi][ni], 0, 0, 0);
                acc1[mi][ni] = __builtin_amdgcn_mfma_f32_16x16x32_bf16(al[mi], bh[ni], acc1[mi][ni], 0, 0, 0);
            }
    }
    __syncthreads();

    // ---- t = relu(acc1 + b1) -> split-bf16 t-frags in LDS ----
#pragma unroll
    for (int ni = 0; ni < 4; ni++) {
        int col = bcol + ni * 16 + lr;
        float bv = b1[col];
        int sl2 = col >> 3, i = col & 7;
#pragma unroll
        for (int mi = 0; mi < 2; mi++)
#pragma unroll
            for (int j = 0; j < 4; j++) {
                int r = mi * 16 + lg * 4 + j;
                float o = fmaxf(acc1[mi][ni][j] + bv, 0.f);
                short hh = f2bf(o);
                short hl = f2bf(o - bf2f(hh));
                LB[(sl2 * 33 + r) * 8 + i] = hh;
                LB[8448 + (sl2 * 33 + r) * 8 + i] = hl;
            }
    }
    __syncthreads();

    // ---- stage 2 MFMA: out = t@W2, K=256 ----
    f32x4 acc2[2][4] = {};
#pragma unroll
    for (int s = 0; s < 8; s++) {
        int sl = s * 4 + lg;
        bf16x8 ah[2], al[2], bh[4], bl[4];
#pragma unroll
        for (int mi = 0; mi < 2; mi++) {
            ah[mi] = *(bf16x8*)&LB[(sl * 33 + mi * 16 + lr) * 8];
            al[mi] = *(bf16x8*)&LB[8448 + (sl * 33 + mi * 16 + lr) * 8];
        }
        const short* pbh = PB2h + ((size_t)sl * 256 + bcol + lr) * 8;
        const short* pbl = PB2l + ((size_t)sl * 256 + bcol + lr) * 8;
#pragma unroll
        for (int ni = 0; ni < 4; ni++) {
            bh[ni] = *(const bf16x8*)(pbh + ni * 128);
            bl[ni] = *(const bf16x8*)(pbl + ni * 128);
        }
#pragma unroll
        for (int mi = 0; mi < 2; mi++)
#pragma unroll
            for (int ni = 0; ni < 4; ni++) {
                acc2[mi][ni] = __builtin_amdgcn_mfma_f32_16x16x32_bf16(ah[mi], bh[ni], acc2[mi][ni], 0, 0, 0);
                acc2[mi][ni] = __builtin_amdgcn_mfma_f32_16x16x32_bf16(ah[mi], bl[ni], acc2[mi][ni], 0, 0, 0);
                acc2[mi][ni] = __builtin_amdgcn_mfma_f32_16x16x32_bf16(al[mi], bh[ni], acc2[mi][ni], 0, 0, 0);
            }
    }
    __syncthreads();

    // ---- epilogue: dinv * (acc2 + b2) -> fp16 tile [32][256] in LDS ----
    float dvo[2][4];
#pragma unroll
    for (int mi = 0; mi < 2; mi++)
#pragma unroll
        for (int j = 0; j < 4; j++) {
            int row = brow + mi * 16 + lg * 4 + j;
            dvo[mi][j] = (row < n) ? dinv[row] : 0.f;
        }
#pragma unroll
    for (int ni = 0; ni < 4; ni++) {
        int col = bcol + ni * 16 + lr;
        float bv = b2[col];
#pragma unroll
        for (int mi = 0; mi < 2; mi++)
#pragma unroll
            for (int j = 0; j < 4; j++) {
                int r = mi * 16 + lg * 4 + j;
                float o = (acc2[mi][ni][j] + bv) * dvo[mi][j];
                *(__half*)&LB[r * 256 + col] = __float2half_rn(o);
            }
    }
    __syncthreads();

    // ---- cooperative write-out: 1024 x 16B chunks (512B/row) ----
#pragma unroll
    for (int q = 0; q < 4; q++) {
        int idx = t + q * 256;          // [0,1024)
        int row = idx >> 5, c = idx & 31;
        int vv = brow + row;
        if (vv < n)
            *(uint4*)(Aout + (size_t)vv * 256 + c * 8) = *(const uint4*)&LB[row * 256 + c * 8];
    }
}

// ---------------- fused GCN layer: out = relu((S@h)@Wc + b) -------------------
// Input hpack fp16 PRE-SCALED by dinv => gather is a pure fp16 row sum.
// BM=16 rows/block, 4 waves; 8-deep gather (8x8B in flight per lane).
// LDS aliased: bf16 A-frags (8704 sh) / fp16 out tile (4096 sh).

template<bool SCALE_OUT>
__global__ __launch_bounds__(256) void layer_fused(const short* __restrict__ Ain,
                                                   const int* __restrict__ row_ptr, const int* __restrict__ adj,
                                                   const float* __restrict__ dinv,
                                                   const short* __restrict__ PBh, const short* __restrict__ PBl,
                                                   const float* __restrict__ bias,
                                                   short* __restrict__ Aout, int n) {
    __shared__ short LB[8704];
    int t = threadIdx.x, lane = t & 63, wv = t >> 6;
    int lr = lane & 15, lg = lane >> 4;
    int brow = blockIdx.x * 16;
    int slab = lane >> 1, i0 = (lane & 1) * 4;
    int loff = lane * 4;                            // fp16 col base (4 cols/lane)

    // ---- phase 1: gather + sum (each wave: 4 dst rows) ----
    for (int it = 0; it < 4; ++it) {
        int r = wv * 4 + it, v = brow + r;
        if (v >= n) break;                          // wave-uniform
        float dv = dinv[v];
        uint2 V0 = *(const uint2*)(Ain + (size_t)v * 256 + loff);
        float4 acc = make_float4(0.f, 0.f, 0.f, 0.f);
        HADD(V0);
        int e = row_ptr[v], end = row_ptr[v + 1];
        for (; e + 8 <= end; e += 8) {
            int s8[8]; uint2 V[8];
#pragma unroll
            for (int j = 0; j < 8; j++) s8[j] = adj[e + j];
#pragma unroll
            for (int j = 0; j < 8; j++) V[j] = *(const uint2*)(Ain + (size_t)s8[j] * 256 + loff);
#pragma unroll
            for (int j = 0; j < 8; j++) HADD(V[j]);
        }
        for (; e + 4 <= end; e += 4) {
            int s4[4]; uint2 V[4];
#pragma unroll
            for (int j = 0; j < 4; j++) s4[j] = adj[e + j];
#pragma unroll
            for (int j = 0; j < 4; j++) V[j] = *(const uint2*)(Ain + (size_t)s4[j] * 256 + loff);
#pragma unroll
            for (int j = 0; j < 4; j++) HADD(V[j]);
        }
        for (; e < end; e++) {
            uint2 V = *(const uint2*)(Ain + (size_t)adj[e] * 256 + loff);
            HADD(V);
        }
        uint2 hw, lw;
        split2(dv * acc.x, dv * acc.y, dv * acc.z, dv * acc.w, hw, lw);
        *(uint2*)&LB[(slab * 17 + r) * 8 + i0] = hw;
        *(uint2*)&LB[4352 + (slab * 17 + r) * 8 + i0] = lw;
    }
    __syncthreads();

    // ---- phase 2: 3-term MFMA, wave wv -> cols [wv*64, wv*64+64) ----
    int bcol = wv * 64;
    f32x4 acc2[4] = {};
#pragma unroll
    for (int s = 0; s < 8; ++s) {
        int sl = s * 4 + lg;
        bf16x8 ah = *(bf16x8*)&LB[(sl * 17 + lr) * 8];
        bf16x8 al = *(bf16x8*)&LB[4352 + (sl * 17 + lr) * 8];
        const short* pbh = PBh + ((size_t)sl * 256 + bcol + lr) * 8;
        const short* pbl = PBl + ((size_t)sl * 256 + bcol + lr) * 8;
        bf16x8 bh[4], bl[4];
#pragma unroll
        for (int ni = 0; ni < 4; ni++) {
            bh[ni] = *(const bf16x8*)(pbh + ni * 128);
            bl[ni] = *(const bf16x8*)(pbl + ni * 128);
        }
#pragma unroll
        for (int ni = 0; ni < 4; ni++) {
            acc2[ni] = __builtin_amdgcn_mfma_f32_16x16x32_bf16(ah, bh[ni], acc2[ni], 0, 0, 0);
            acc2[ni] = __builtin_amdgcn_mfma_f32_16x16x32_bf16(ah, bl[ni], acc2[ni], 0, 0, 0);
            acc2[ni] = __builtin_amdgcn_mfma_f32_16x16x32_bf16(al, bh[ni], acc2[ni], 0, 0, 0);
        }
    }
    __syncthreads();   // all LDS A-frag reads done; safe to reuse buffer

    // ---- epilogue: relu(acc+bias) [*dinv] -> fp16 tile [16][256] in LDS ----
    float dvo[4];
    if (SCALE_OUT) {
#pragma unroll
        for (int j = 0; j < 4; j++) {
            int row = brow + lg * 4 + j;
            dvo[j] = (row < n) ? dinv[row] : 0.f;
        }
    }
#pragma unroll
    for (int ni = 0; ni < 4; ni++) {
        int col = bcol + ni * 16 + lr;
        float bv = bias[col];
#pragma unroll
        for (int j = 0; j < 4; j++) {
            int r = lg * 4 + j;
            float o = fmaxf(acc2[ni][j] + bv, 0.f);
            if (SCALE_OUT) o *= dvo[j];
            *(__half*)&LB[r * 256 + col] = __float2half_rn(o);
        }
    }
    __syncthreads();

    // ---- cooperative write-out: 512 x 16B chunks (512B/row) ----
#pragma unroll
    for (int q = 0; q < 2; q++) {
        int idx = t + q * 256;          // [0,512)
        int row = idx >> 5, c = idx & 31;
        int vv = brow + row;
        if (vv < n)
            *(uint4*)(Aout + (size_t)vv * 256 + c * 8) = *(const uint4*)&LB[row * 256 + c * 8];
    }
}

// ---------------- pooling (mean + max over rows) from hpack fp16 --------------

__global__ __launch_bounds__(256) void pool_packed(const short* __restrict__ P, int n,
                                                   float* __restrict__ pool_sum, int* __restrict__ pool_max) {
    int t = threadIdx.x;   // column
    int chunk = (n + gridDim.x - 1) / gridDim.x;
    int r0 = blockIdx.x * chunk, r1 = min(n, r0 + chunk);
    float s = 0.f, mx = 0.f;
    for (int r = r0; r < r1; r++) {
        float v = __half2float(*(const __half*)&P[(size_t)r * 256 + t]);
        s += v;
        mx = fmaxf(mx, v);
    }
    atomicAdd(&pool_sum[t], s);
    atomicMax(&pool_max[t], __float_as_int(mx));
}

// ---------------- final MLP head (single block) ----------------

__global__ __launch_bounds__(256) void mlp_head(const float* __restrict__ pool_sum, const int* __restrict__ pool_max,
                                                const float* __restrict__ Wp1, const float* __restrict__ bp1,
                                                const float* __restrict__ Wp2, const float* __restrict__ bp2,
                                                float* __restrict__ out, float invn) {
    __shared__ float g[2 * HID];
    __shared__ float hid[HID];
    int t = threadIdx.x;
    g[t] = pool_sum[t] * invn;
    g[HID + t] = __int_as_float(pool_max[t]);
    __syncthreads();
    float acc = bp1[t];
#pragma unroll 8
    for (int j = 0; j < 2 * HID; j++) acc = fmaf(g[j], Wp1[j * HID + t], acc);
    hid[t] = fmaxf(acc, 0.f);
    __syncthreads();
    if (t < DEMB) {
        float a2 = bp2[t];
#pragma unroll 8
        for (int j = 0; j < HID; j++) a2 = fmaf(hid[j], Wp2[j * DEMB + t], a2);
        out[t] = a2;
    }
}

// ---------------- launcher ----------------

extern "C" void kernel_launch(void* const* d_in, const int* in_sizes, int n_in,
                              void* d_out, int out_size, void* d_ws, size_t ws_size,
                              hipStream_t stream) {
    const float* x   = (const float*)d_in[0];
    const int*   ei  = (const int*)d_in[1];
    const float* W1  = (const float*)d_in[2];
    const float* b1  = (const float*)d_in[3];
    const float* W2  = (const float*)d_in[4];
    const float* b2  = (const float*)d_in[5];
    const float* Wc  = (const float*)d_in[6];
    const float* bc  = (const float*)d_in[7];
    const float* Wp1 = (const float*)d_in[8];
    const float* bp1 = (const float*)d_in[9];
    const float* Wp2 = (const float*)d_in[10];
    const float* bp2 = (const float*)d_in[11];
    float* out = (float*)d_out;

    int N = in_sizes[0] / FIN;
    int E = in_sizes[1] / 2;
    int nb32 = (N + 31) / 32;
    int nb16 = (N + 15) / 16;
    int R = nb32 * 32;                   // padded rows for hpack buffers

    char* base = (char*)d_ws;
    short* actA = (short*)base;                          // [R,256] fp16 hpack
    short* actB = (short*)(base + (size_t)R * 512);      // [R,256] fp16 hpack
    int*   counts  = (int*)(base + 2 * (size_t)R * 512); // [N]
    int*   row_ptr = counts + N;                         // [N+1]
    int*   cursor  = row_ptr + (N + 1);                  // [N]
    int*   adj     = cursor + N;                         // [E]
    float* dinvp   = (float*)(adj + E);                  // [N]
    float* pool_sum = dinvp + N;                         // [HID]
    int*   pool_max = (int*)(pool_sum + HID);            // [HID]
    int*   chunkSums = pool_max + HID;                   // [<=64]
    short* PH = (short*)((((uintptr_t)(chunkSums + 64)) + 15) & ~(uintptr_t)15);
    short* PL = PH + 278528;
    const int oW1 = 0, oW2 = 16384, oC0 = 81920, oC1 = 147456, oC2 = 212992;

    int nch = (N + 1023) / 1024;
    int nb256 = (N + 255) / 256;
    int eb256 = (E + 255) / 256;

    zero_kernel<<<nb256, 256, 0, stream>>>(counts, N, pool_sum, pool_max);
    hist_kernel<<<eb256, 256, 0, stream>>>(ei, E, counts);
    scan_partial<<<nch, 256, 0, stream>>>(counts, N, chunkSums, dinvp);
    scan_sums<<<1, 64, 0, stream>>>(chunkSums, nch);
    scan_final<<<nch, 256, 0, stream>>>(counts, N, chunkSums, row_ptr, cursor);
    fill_kernel<<<eb256, 256, 0, stream>>>(ei, E, cursor, adj);

    pack_all<<<64 + 4 * 256, 256, 0, stream>>>(W1, W2, Wc, PH, PL);

    // fused encoder: actA = hpack(dinv * (relu(x@W1+b1)@W2 + b2))
    encoder_fused<<<nb32, 256, 0, stream>>>(x, PH + oW1, PL + oW1, PH + oW2, PL + oW2,
                                            b1, b2, dinvp, actA, N);

    // fused GCN layers: out = relu((S@h)@Wc + bc); pre-scaled except last
    layer_fused<true><<<nb16, 256, 0, stream>>>(actA, row_ptr, adj, dinvp, PH + oC0, PL + oC0, bc + 0 * HID, actB, N);
    layer_fused<true><<<nb16, 256, 0, stream>>>(actB, row_ptr, adj, dinvp, PH + oC1, PL + oC1, bc + 1 * HID, actA, N);
    layer_fused<false><<<nb16, 256, 0, stream>>>(actA, row_ptr, adj, dinvp, PH + oC2, PL + oC2, bc + 2 * HID, actB, N);

    // pooling + head
    pool_packed<<<256, 256, 0, stream>>>(actB, N, pool_sum, pool_max);
    mlp_head<<<1, 256, 0, stream>>>(pool_sum, pool_max, Wp1, bp1, Wp2, bp2, out, 1.0f / (float)N);
}